// Round 4
// baseline (732.929 us; speedup 1.0000x reference)
//
#include <hip/hip_runtime.h>
#include <math.h>

#define H 128
#define W 128
#define NB 8
#define NFC 64

typedef __attribute__((ext_vector_type(8))) short s16x8;
typedef __attribute__((ext_vector_type(4))) short s16x4;
typedef __attribute__((ext_vector_type(4))) float f32x4;
typedef __attribute__((ext_vector_type(4))) int   i32x4;

__device__ __forceinline__ float b2f(short s) {
    return __uint_as_float(((unsigned)(unsigned short)s) << 16);
}
__device__ __forceinline__ short f2bf(float f) {
    unsigned u = __float_as_uint(f);
    u += 0x7FFF + ((u >> 16) & 1);
    return (short)(u >> 16);
}
__device__ __forceinline__ short f2h(float f) {
    _Float16 h = (_Float16)f;
    return __builtin_bit_cast(short, h);
}
__device__ __forceinline__ float h2f(short s) {
    return (float)__builtin_bit_cast(_Float16, s);
}

// ---------------------------------------------------------------------------
// weight transform: w fp32 [OC][IC][3][3] -> wT bf16 [OCpad][9][64]
// ---------------------------------------------------------------------------
__global__ __launch_bounds__(256) void k_wt(const float* __restrict__ w,
                                            short* __restrict__ wT,
                                            int OC, int IC, int icoff)
{
    int idx = blockIdx.x * 256 + threadIdx.x;
    int o = idx / 576;
    int r = idx - o * 576;
    int t = r >> 6, i = r & 63;
    float v = (o < OC) ? w[((size_t)o * IC + icoff + i) * 9 + t] : 0.f;
    wT[idx] = f2bf(v);
}

// ---------------------------------------------------------------------------
// NCHW fp32 -> NHWC bf16
// ---------------------------------------------------------------------------
__global__ __launch_bounds__(256) void k_nhwc(const float* __restrict__ src,
                                              short* __restrict__ dst)
{
    int px = blockIdx.x * 256 + threadIdx.x;
    int n = px >> 14;
    int sp = px & 16383;
    const float* s = src + (size_t)n * 64 * 16384 + sp;
    unsigned pk[32];
    #pragma unroll
    for (int c = 0; c < 32; ++c) {
        float v0 = s[(size_t)(2 * c) * 16384];
        float v1 = s[(size_t)(2 * c + 1) * 16384];
        pk[c] = (unsigned)(unsigned short)f2bf(v0) |
                ((unsigned)(unsigned short)f2bf(v1) << 16);
    }
    i32x4* d = (i32x4*)(dst + (size_t)px * 64);
    #pragma unroll
    for (int qq = 0; qq < 8; ++qq) {
        i32x4 t;
        t[0] = pk[4 * qq]; t[1] = pk[4 * qq + 1];
        t[2] = pk[4 * qq + 2]; t[3] = pk[4 * qq + 3];
        d[qq] = t;
    }
}

// ---------------------------------------------------------------------------
// backwarp: nbrH (NHWC bf16) + flow -> warped (NHWC bf16)
// ---------------------------------------------------------------------------
__global__ __launch_bounds__(256) void k_backwarp(const short* __restrict__ nbrH,
                                                  const float* __restrict__ flow,
                                                  short* __restrict__ warped)
{
    int idx = blockIdx.x * 256 + threadIdx.x;
    int px = idx >> 2, qt = idx & 3;
    int n = px >> 14;
    int x = px & 127, y = (px >> 7) & 127;
    float fx = flow[(size_t)(n * 2 + 0) * 16384 + y * 128 + x];
    float fy = flow[(size_t)(n * 2 + 1) * 16384 + y * 128 + x];
    float pxf = (float)x + fx, pyf = (float)y + fy;
    float x0f = floorf(pxf), y0f = floorf(pyf);
    int x0 = (int)x0f, y0 = (int)y0f;
    float dx = pxf - x0f, dy = pyf - y0f;
    float vy0 = ((unsigned)y0 < 128u) ? 1.f : 0.f;
    float vy1 = ((unsigned)(y0 + 1) < 128u) ? 1.f : 0.f;
    float vx0 = ((unsigned)x0 < 128u) ? 1.f : 0.f;
    float vx1 = ((unsigned)(x0 + 1) < 128u) ? 1.f : 0.f;
    float w00 = (1.f - dy) * (1.f - dx) * vy0 * vx0;
    float w01 = (1.f - dy) * dx * vy0 * vx1;
    float w10 = dy * (1.f - dx) * vy1 * vx0;
    float w11 = dy * dx * vy1 * vx1;
    int y0c = min(max(y0, 0), 127), y1c = min(max(y0 + 1, 0), 127);
    int x0c = min(max(x0, 0), 127), x1c = min(max(x0 + 1, 0), 127);
    const short* nb = nbrH + (size_t)n * 16384 * 64 + qt * 16;
    const short* p00 = nb + (y0c * 128 + x0c) * 64;
    const short* p01 = nb + (y0c * 128 + x1c) * 64;
    const short* p10 = nb + (y1c * 128 + x0c) * 64;
    const short* p11 = nb + (y1c * 128 + x1c) * 64;
    s16x8 a00 = *(const s16x8*)p00, b00 = *(const s16x8*)(p00 + 8);
    s16x8 a01 = *(const s16x8*)p01, b01 = *(const s16x8*)(p01 + 8);
    s16x8 a10 = *(const s16x8*)p10, b10 = *(const s16x8*)(p10 + 8);
    s16x8 a11 = *(const s16x8*)p11, b11 = *(const s16x8*)(p11 + 8);
    s16x8 r0, r1;
    #pragma unroll
    for (int c = 0; c < 8; ++c) {
        float v = w00 * b2f(a00[c]) + w01 * b2f(a01[c]) + w10 * b2f(a10[c]) + w11 * b2f(a11[c]);
        r0[c] = f2bf(v);
        float u = w00 * b2f(b00[c]) + w01 * b2f(b01[c]) + w10 * b2f(b10[c]) + w11 * b2f(b11[c]);
        r1[c] = f2bf(u);
    }
    short* o = warped + (size_t)px * 64 + qt * 16;
    *(s16x8*)o = r0;
    *(s16x8*)(o + 8) = r1;
}

// ---------------------------------------------------------------------------
// MFMA conv3x3. Block = 128 px (16w x 8h), 4 waves; wave: 64oc x 32px.
// A-frags direct from global (L2-hot) -> single barrier per block.
// MODE 1: dual-input (conv1: warped||ref, wT = [2][64][9][64])
// MODE 2: single input -> bias+lrelu -> bf16
// MODE 3: conv4 epilogue -> offmask fp16 (og = blockIdx.y, 4-image chunk n0)
// ---------------------------------------------------------------------------
template<int MODE>
__global__ __launch_bounds__(256) void k_conv(
    const short* __restrict__ in0, const short* __restrict__ in1,
    const short* __restrict__ wT, const float* __restrict__ bias,
    short* __restrict__ outB,
    short* __restrict__ offmask, const float* __restrict__ flow, int n0)
{
    constexpr int NT = (MODE == 1) ? 2 : 1;
    __shared__ __align__(16) short tileS[NT * 180 * 64];

    int tid = threadIdx.x;
    int bid = blockIdx.x;
    int og = (MODE == 3) ? blockIdx.y : 0;
    int n  = (MODE == 3) ? (n0 + (bid >> 7)) : (bid >> 7);
    int tl = bid & 127;
    int bx = (tl & 7) << 4;
    int by = (tl >> 3) << 3;
    int ln = tid & 63, wv = tid >> 6;
    int c = ln & 15, q = ln >> 4;

    for (int i = tid; i < NT * 1440; i += 256) {
        int half = i / 1440;
        int ii = i - half * 1440;
        int pt = ii >> 3, c16 = ii & 7;
        int ty = pt / 18, tx = pt - ty * 18;
        int gy = by + ty - 1, gx = bx + tx - 1;
        i32x4 v = {0, 0, 0, 0};
        if ((unsigned)gy < 128u && (unsigned)gx < 128u) {
            const short* src = (half == 0) ? in0 : in1;
            v = *(const i32x4*)(src + (((size_t)n * 128 + gy) * 128 + gx) * 64 + c16 * 8);
        }
        *(i32x4*)((char*)tileS + half * 23040 + pt * 128 + ((c16 ^ (pt & 7)) << 4)) = v;
    }

    f32x4 acc[4][2];
    #pragma unroll
    for (int m = 0; m < 4; ++m) {
        acc[m][0] = (f32x4){0.f, 0.f, 0.f, 0.f};
        acc[m][1] = (f32x4){0.f, 0.f, 0.f, 0.f};
    }

    int p0 = 2 * wv, p1 = 2 * wv + 1;
    int pby0 = (p0 >> 2) << 2, pbx0 = (p0 & 3) << 2;
    int pby1 = (p1 >> 2) << 2, pbx1 = (p1 & 3) << 2;
    int cy = c >> 2, cx = c & 3;

    __syncthreads();

    #pragma unroll
    for (int half = 0; half < NT; ++half) {
        const short* wb = wT + ((MODE == 3) ? (size_t)og * 36864 : (size_t)half * 36864);
        const char* tb = (const char*)tileS + half * 23040;
        #pragma unroll
        for (int tap = 0; tap < 9; ++tap) {
            int dty = tap / 3, dtx = tap - dty * 3;
            int pta = (pby0 + cy + dty) * 18 + pbx0 + cx + dtx;
            int ptb = (pby1 + cy + dty) * 18 + pbx1 + cx + dtx;
            #pragma unroll
            for (int ih = 0; ih < 2; ++ih) {
                int slot = ih * 4 + q;
                s16x8 bf0 = *(const s16x8*)(tb + pta * 128 + ((slot ^ (pta & 7)) << 4));
                s16x8 bf1 = *(const s16x8*)(tb + ptb * 128 + ((slot ^ (ptb & 7)) << 4));
                #pragma unroll
                for (int m = 0; m < 4; ++m) {
                    s16x8 a = *(const s16x8*)(wb + (size_t)(m * 16 + c) * 576 + tap * 64 + ih * 32 + q * 8);
                    acc[m][0] = __builtin_amdgcn_mfma_f32_16x16x32_bf16(a, bf0, acc[m][0], 0, 0, 0);
                    acc[m][1] = __builtin_amdgcn_mfma_f32_16x16x32_bf16(a, bf1, acc[m][1], 0, 0, 0);
                }
            }
        }
    }

    #pragma unroll
    for (int p = 0; p < 2; ++p) {
        int pby = p ? pby1 : pby0;
        int pbx = p ? pbx1 : pbx0;
        int y = by + pby + cy;
        int x = bx + pbx + cx;
        size_t pxi = ((size_t)n * 128 + y) * 128 + x;
        float fy = 0.f, fx2 = 0.f;
        if (MODE == 3) {
            fy  = flow[(size_t)(n * 2 + 1) * 16384 + y * 128 + x];
            fx2 = flow[(size_t)(n * 2 + 0) * 16384 + y * 128 + x];
        }
        #pragma unroll
        for (int m = 0; m < 4; ++m) {
            int o0 = m * 16 + q * 4;
            f32x4 v = acc[m][p];
            if (MODE == 1 || MODE == 2) {
                f32x4 bv = *(const f32x4*)(bias + o0);
                v += bv;
                s16x4 r;
                #pragma unroll
                for (int j = 0; j < 4; ++j) {
                    float t = v[j];
                    t = t >= 0.f ? t : 0.1f * t;
                    r[j] = f2bf(t);
                }
                *(s16x4*)(outB + pxi * 64 + o0) = r;
            } else {
                int oc4 = og * 64 + o0;
                if (oc4 < 432) {
                    f32x4 bv = *(const f32x4*)(bias + oc4);
                    v += bv;
                    s16x4 r;
                    if (oc4 < 288) {
                        v[0] += fy; v[1] += fx2; v[2] += fy; v[3] += fx2;
                        #pragma unroll
                        for (int j = 0; j < 4; ++j) r[j] = f2h(v[j]);
                    } else {
                        #pragma unroll
                        for (int j = 0; j < 4; ++j) r[j] = f2h(1.f / (1.f + expf(-v[j])));
                    }
                    size_t nrel = (size_t)(bid >> 7);
                    *(s16x4*)(offmask + (nrel * 16384 + y * 128 + x) * 432 + oc4) = r;
                }
            }
        }
    }
}

// ---------------------------------------------------------------------------
// DCN: block = 4 waves = 2 patches x 2 K-halves. Each wave samples its taps
// into B-frags in regs, MFMA-accumulates; wave pair reduces via LDS.
// ---------------------------------------------------------------------------
__device__ __forceinline__ void dcn_tap(
    int tap, int y, int x, int q, int c,
    const short* __restrict__ om, const short* __restrict__ nb,
    const short* __restrict__ dcwT, f32x4 acc[4])
{
    int dty = tap / 3 - 1, dtx = tap - (tap / 3) * 3 - 1;
    #pragma unroll
    for (int ih = 0; ih < 2; ++ih) {
        s16x8 bf;
        #pragma unroll
        for (int hh = 0; hh < 2; ++hh) {
            int g = ih * 8 + q * 2 + hh;
            int gk = g * 9 + tap;
            int dd = *(const int*)(om + 2 * gk);
            float dyv = h2f((short)(dd & 0xffff));
            float dxv = h2f((short)(dd >> 16));
            float mk  = h2f(om[288 + gk]);
            float sy = (float)(y + dty) + dyv;
            float sx = (float)(x + dtx) + dxv;
            float y0f = floorf(sy), x0f = floorf(sx);
            int y0 = (int)y0f, x0 = (int)x0f;
            float ddy = sy - y0f, ddx = sx - x0f;
            float vy0 = ((unsigned)y0 < 128u) ? 1.f : 0.f;
            float vy1 = ((unsigned)(y0 + 1) < 128u) ? 1.f : 0.f;
            float vx0 = ((unsigned)x0 < 128u) ? 1.f : 0.f;
            float vx1 = ((unsigned)(x0 + 1) < 128u) ? 1.f : 0.f;
            float w00 = (1.f - ddy) * (1.f - ddx) * vy0 * vx0;
            float w01 = (1.f - ddy) * ddx * vy0 * vx1;
            float w10 = ddy * (1.f - ddx) * vy1 * vx0;
            float w11 = ddy * ddx * vy1 * vx1;
            int y0c = min(max(y0, 0), 127), y1c = min(max(y0 + 1, 0), 127);
            int x0c = min(max(x0, 0), 127), x1c = min(max(x0 + 1, 0), 127);
            s16x4 v00 = *(const s16x4*)(nb + (y0c * 128 + x0c) * 64 + g * 4);
            s16x4 v01 = *(const s16x4*)(nb + (y0c * 128 + x1c) * 64 + g * 4);
            s16x4 v10 = *(const s16x4*)(nb + (y1c * 128 + x0c) * 64 + g * 4);
            s16x4 v11 = *(const s16x4*)(nb + (y1c * 128 + x1c) * 64 + g * 4);
            #pragma unroll
            for (int cc = 0; cc < 4; ++cc) {
                float sv = w00 * b2f(v00[cc]) + w01 * b2f(v01[cc]) +
                           w10 * b2f(v10[cc]) + w11 * b2f(v11[cc]);
                bf[hh * 4 + cc] = f2bf(sv * mk);
            }
        }
        int ic0 = ih * 32 + q * 8;
        #pragma unroll
        for (int m = 0; m < 4; ++m) {
            s16x8 a = *(const s16x8*)(dcwT + ((size_t)(m * 16 + c) * 9 + tap) * 64 + ic0);
            acc[m] = __builtin_amdgcn_mfma_f32_16x16x32_bf16(a, bf, acc[m], 0, 0, 0);
        }
    }
}

__global__ __launch_bounds__(256) void k_dcn(
    const short* __restrict__ offmask, const short* __restrict__ nbrH,
    const short* __restrict__ dcwT, const float* __restrict__ dcb,
    float* __restrict__ out, int n0)
{
    __shared__ __align__(16) float red[2][64][20];

    int tid = threadIdx.x;
    int ln = tid & 63, wv = tid >> 6;
    int pll = wv >> 1, khalf = wv & 1;
    int patch = blockIdx.x * 2 + pll;
    int nrel = patch >> 10;
    int pl = patch & 1023;
    int by = (pl >> 5) << 2, bx = (pl & 31) << 2;
    int n = n0 + nrel;
    int c = ln & 15, q = ln >> 4;
    int y = by + (c >> 2), x = bx + (c & 3);
    const short* om = offmask + ((size_t)nrel * 16384 + y * 128 + x) * 432;
    const short* nb = nbrH + (size_t)n * 16384 * 64;

    f32x4 acc[4];
    #pragma unroll
    for (int m = 0; m < 4; ++m) acc[m] = (f32x4){0.f, 0.f, 0.f, 0.f};

    if (khalf == 0) {
        #pragma unroll
        for (int t = 0; t < 5; ++t) dcn_tap(t, y, x, q, c, om, nb, dcwT, acc);
    } else {
        #pragma unroll
        for (int t = 5; t < 9; ++t) dcn_tap(t, y, x, q, c, om, nb, dcwT, acc);
    }

    if (khalf == 1) {
        #pragma unroll
        for (int m = 0; m < 4; ++m)
            *(f32x4*)&red[pll][ln][m * 4] = acc[m];
    }
    __syncthreads();
    if (khalf == 0) {
        #pragma unroll
        for (int m = 0; m < 4; ++m) {
            f32x4 o = *(const f32x4*)&red[pll][ln][m * 4];
            acc[m] += o;
        }
        #pragma unroll
        for (int m = 0; m < 4; ++m) {
            int o0 = m * 16 + q * 4;
            f32x4 bv = *(const f32x4*)(dcb + o0);
            f32x4 v = acc[m] + bv;
            #pragma unroll
            for (int j = 0; j < 4; ++j) {
                float t = v[j];
                t = t >= 0.f ? t : 0.1f * t;
                out[((size_t)n * 64 + o0 + j) * 16384 + y * 128 + x] = t;
            }
        }
    }
}

// ---------------------------------------------------------------------------
extern "C" void kernel_launch(void* const* d_in, const int* in_sizes, int n_in,
                              void* d_out, int out_size, void* d_ws, size_t ws_size,
                              hipStream_t stream)
{
    const float* nbr  = (const float*)d_in[0];
    const float* ref  = (const float*)d_in[1];
    const float* flow = (const float*)d_in[2];
    const float* w1   = (const float*)d_in[3];
    const float* b1   = (const float*)d_in[4];
    const float* w2   = (const float*)d_in[5];
    const float* b2   = (const float*)d_in[6];
    const float* w3   = (const float*)d_in[7];
    const float* b3   = (const float*)d_in[8];
    const float* w4   = (const float*)d_in[9];
    const float* b4   = (const float*)d_in[10];
    const float* dcw  = (const float*)d_in[11];
    const float* dcb  = (const float*)d_in[12];
    float* out = (float*)d_out;
    char* ws = (char*)d_ws;

    // ws layout (bytes), peak 91.24 MB (round-0 proved >=100.6 MB usable):
    //   nbrH    [0,        16777216)   live whole run
    //   wpool   [16777216, 17661952)   weight transforms
    //   warped  [17825792, 34603008)   -> dead after conv1; h2 lives here after conv2
    //   refH    [34603008, 51380224)   -> dead after conv1; h3 input staging
    //   h1      [51380224, 68157440)   -> dead after conv2
    //   offmask [17825792, 74448896)   conv4/dcn phase only (overlaps dead bufs)
    //   h3      [74448896, 91226112)   live until last conv4
    short* nbrH   = (short*)ws;
    short* wpool  = (short*)(ws + 16777216);
    short* warped = (short*)(ws + 17825792);
    short* refH   = (short*)(ws + 34603008);
    short* h1     = (short*)(ws + 51380224);
    short* h2     = warped;
    short* offmask= (short*)(ws + 17825792);
    short* h3     = (short*)(ws + 74448896);

    short* wT1  = wpool;            // [2][64][9][64]
    short* wT2  = wpool + 73728;
    short* wT3  = wpool + 110592;
    short* wT4  = wpool + 147456;   // [448][9][64]
    short* dcwT = wpool + 405504;

    k_wt<<<144, 256, 0, stream>>>(w1, wT1, 64, 128, 0);
    k_wt<<<144, 256, 0, stream>>>(w1, wT1 + 36864, 64, 128, 64);
    k_wt<<<144, 256, 0, stream>>>(w2, wT2, 64, 64, 0);
    k_wt<<<144, 256, 0, stream>>>(w3, wT3, 64, 64, 0);
    k_wt<<<1008, 256, 0, stream>>>(w4, wT4, 432, 64, 0);
    k_wt<<<144, 256, 0, stream>>>(dcw, dcwT, 64, 64, 0);

    k_nhwc<<<512, 256, 0, stream>>>(nbr, nbrH);
    k_nhwc<<<512, 256, 0, stream>>>(ref, refH);
    k_backwarp<<<2048, 256, 0, stream>>>(nbrH, flow, warped);

    k_conv<1><<<1024, 256, 0, stream>>>(warped, refH, wT1, b1, h1, nullptr, nullptr, 0);
    k_conv<2><<<1024, 256, 0, stream>>>(h1, nullptr, wT2, b2, h2, nullptr, nullptr, 0);
    k_conv<2><<<1024, 256, 0, stream>>>(h2, nullptr, wT3, b3, h3, nullptr, nullptr, 0);

    for (int n0 = 0; n0 < 8; n0 += 4) {
        dim3 g4(512, 7);
        k_conv<3><<<g4, 256, 0, stream>>>(h3, nullptr, wT4, b4, nullptr, offmask, flow, n0);
        k_dcn<<<2048, 256, 0, stream>>>(offmask, nbrH, dcwT, dcb, out, n0);
    }
}

// Round 6
// 435.890 us; speedup vs baseline: 1.6815x; 1.6815x over previous
//
#include <hip/hip_runtime.h>
#include <math.h>

#define H 128
#define W 128
#define NB 8
#define NFC 64

typedef __attribute__((ext_vector_type(8))) short s16x8;
typedef __attribute__((ext_vector_type(4))) short s16x4;
typedef __attribute__((ext_vector_type(4))) float f32x4;
typedef __attribute__((ext_vector_type(4))) int   i32x4;

__device__ __forceinline__ float b2f(short s) {
    return __uint_as_float(((unsigned)(unsigned short)s) << 16);
}
__device__ __forceinline__ short f2bf(float f) {
    unsigned u = __float_as_uint(f);
    u += 0x7FFF + ((u >> 16) & 1);
    return (short)(u >> 16);
}
__device__ __forceinline__ short f2h(float f) {
    _Float16 h = (_Float16)f;
    return __builtin_bit_cast(short, h);
}
__device__ __forceinline__ float h2f(short s) {
    return (float)__builtin_bit_cast(_Float16, s);
}

// ---------------------------------------------------------------------------
// all weight transforms in one launch -> wpool bf16 [768][9][64]
// units: 0-63 w1 ic0-63, 64-127 w1 ic64-127, 128-191 w2, 192-255 w3,
//        256-703 w4 (432 padded to 448), 704-767 dcw
// pure per-element function of inputs: race-free.
// ---------------------------------------------------------------------------
__global__ __launch_bounds__(256) void k_wt_all(
    const float* __restrict__ w1, const float* __restrict__ w2,
    const float* __restrict__ w3, const float* __restrict__ w4,
    const float* __restrict__ dcw, short* __restrict__ wp)
{
    int idx = blockIdx.x * 256 + threadIdx.x;   // < 442368
    int u = idx / 576;
    int r = idx - u * 576;
    int t = r >> 6, i = r & 63;
    float v;
    if (u < 128) {
        int o = u & 63, icoff = (u >> 6) << 6;
        v = w1[((size_t)(o * 128) + icoff + i) * 9 + t];
    } else if (u < 192) {
        int o = u - 128;
        v = w2[((size_t)(o * 64) + i) * 9 + t];
    } else if (u < 256) {
        int o = u - 192;
        v = w3[((size_t)(o * 64) + i) * 9 + t];
    } else if (u < 704) {
        int o = u - 256;
        v = (o < 432) ? w4[((size_t)(o * 64) + i) * 9 + t] : 0.f;
    } else {
        int o = u - 704;
        v = dcw[((size_t)(o * 64) + i) * 9 + t];
    }
    wp[idx] = f2bf(v);
}

// ---------------------------------------------------------------------------
// NCHW fp32 -> NHWC bf16 for both nbr and ref in one launch (race-free)
// ---------------------------------------------------------------------------
__global__ __launch_bounds__(256) void k_nhwc2(const float* __restrict__ nbr,
                                               const float* __restrict__ ref,
                                               short* __restrict__ nbrH,
                                               short* __restrict__ refH)
{
    int px = blockIdx.x * 256 + threadIdx.x;
    const float* src;
    short* dst;
    if (px < 131072) { src = nbr; dst = nbrH; }
    else             { src = ref; dst = refH; px -= 131072; }
    int n = px >> 14;
    int sp = px & 16383;
    const float* s = src + (size_t)n * 64 * 16384 + sp;
    unsigned pk[32];
    #pragma unroll
    for (int c = 0; c < 32; ++c) {
        float v0 = s[(size_t)(2 * c) * 16384];
        float v1 = s[(size_t)(2 * c + 1) * 16384];
        pk[c] = (unsigned)(unsigned short)f2bf(v0) |
                ((unsigned)(unsigned short)f2bf(v1) << 16);
    }
    i32x4* d = (i32x4*)(dst + (size_t)px * 64);
    #pragma unroll
    for (int qq = 0; qq < 8; ++qq) {
        i32x4 t;
        t[0] = pk[4 * qq]; t[1] = pk[4 * qq + 1];
        t[2] = pk[4 * qq + 2]; t[3] = pk[4 * qq + 3];
        d[qq] = t;
    }
}

// ---------------------------------------------------------------------------
// backwarp: nbrH (NHWC bf16) + flow -> warped (NHWC bf16)
// ---------------------------------------------------------------------------
__global__ __launch_bounds__(256) void k_backwarp(const short* __restrict__ nbrH,
                                                  const float* __restrict__ flow,
                                                  short* __restrict__ warped)
{
    int idx = blockIdx.x * 256 + threadIdx.x;
    int px = idx >> 2, qt = idx & 3;
    int n = px >> 14;
    int x = px & 127, y = (px >> 7) & 127;
    float fx = flow[(size_t)(n * 2 + 0) * 16384 + y * 128 + x];
    float fy = flow[(size_t)(n * 2 + 1) * 16384 + y * 128 + x];
    float pxf = (float)x + fx, pyf = (float)y + fy;
    float x0f = floorf(pxf), y0f = floorf(pyf);
    int x0 = (int)x0f, y0 = (int)y0f;
    float dx = pxf - x0f, dy = pyf - y0f;
    float vy0 = ((unsigned)y0 < 128u) ? 1.f : 0.f;
    float vy1 = ((unsigned)(y0 + 1) < 128u) ? 1.f : 0.f;
    float vx0 = ((unsigned)x0 < 128u) ? 1.f : 0.f;
    float vx1 = ((unsigned)(x0 + 1) < 128u) ? 1.f : 0.f;
    float w00 = (1.f - dy) * (1.f - dx) * vy0 * vx0;
    float w01 = (1.f - dy) * dx * vy0 * vx1;
    float w10 = dy * (1.f - dx) * vy1 * vx0;
    float w11 = dy * dx * vy1 * vx1;
    int y0c = min(max(y0, 0), 127), y1c = min(max(y0 + 1, 0), 127);
    int x0c = min(max(x0, 0), 127), x1c = min(max(x0 + 1, 0), 127);
    const short* nb = nbrH + (size_t)n * 16384 * 64 + qt * 16;
    const short* p00 = nb + (y0c * 128 + x0c) * 64;
    const short* p01 = nb + (y0c * 128 + x1c) * 64;
    const short* p10 = nb + (y1c * 128 + x0c) * 64;
    const short* p11 = nb + (y1c * 128 + x1c) * 64;
    s16x8 a00 = *(const s16x8*)p00, b00 = *(const s16x8*)(p00 + 8);
    s16x8 a01 = *(const s16x8*)p01, b01 = *(const s16x8*)(p01 + 8);
    s16x8 a10 = *(const s16x8*)p10, b10 = *(const s16x8*)(p10 + 8);
    s16x8 a11 = *(const s16x8*)p11, b11 = *(const s16x8*)(p11 + 8);
    s16x8 r0, r1;
    #pragma unroll
    for (int c = 0; c < 8; ++c) {
        float v = w00 * b2f(a00[c]) + w01 * b2f(a01[c]) + w10 * b2f(a10[c]) + w11 * b2f(a11[c]);
        r0[c] = f2bf(v);
        float u = w00 * b2f(b00[c]) + w01 * b2f(b01[c]) + w10 * b2f(b10[c]) + w11 * b2f(b11[c]);
        r1[c] = f2bf(u);
    }
    short* o = warped + (size_t)px * 64 + qt * 16;
    *(s16x8*)o = r0;
    *(s16x8*)(o + 8) = r1;
}

// ---------------------------------------------------------------------------
// MFMA conv3x3, IC=64 (round-3-proven structure). Block = 128 px, 4 waves;
// wave: 64oc x 32px. Per-tap LDS weight staging + register preload.
// MODE 0: store fp32 partial (no bias/act)
// MODE 1: + partial + bias + lrelu -> bf16
// MODE 2: + bias + lrelu -> bf16
// MODE 3: conv4 epilogue -> offmask fp16 (og=blockIdx.y, 4-img chunk n0)
// ---------------------------------------------------------------------------
template<int MODE>
__global__ __launch_bounds__(256) void k_conv(
    const short* __restrict__ in, const short* __restrict__ wT,
    const float* __restrict__ bias,
    float* __restrict__ partial, short* __restrict__ outB,
    short* __restrict__ offmask, const float* __restrict__ flow, int n0)
{
    __shared__ __align__(16) short tileS[180 * 64];
    __shared__ __align__(16) short aS[64 * 64];

    int tid = threadIdx.x;
    int bid = blockIdx.x;
    int og = (MODE == 3) ? blockIdx.y : 0;
    int n  = (MODE == 3) ? (n0 + (bid >> 7)) : (bid >> 7);
    int tl = bid & 127;
    int bx = (tl & 7) << 4;
    int by = (tl >> 3) << 3;
    int ln = tid & 63, wv = tid >> 6;
    int c = ln & 15, q = ln >> 4;

    for (int i = tid; i < 1440; i += 256) {
        int pt = i >> 3, c16 = i & 7;
        int ty = pt / 18, tx = pt - ty * 18;
        int gy = by + ty - 1, gx = bx + tx - 1;
        i32x4 v = {0, 0, 0, 0};
        if ((unsigned)gy < 128u && (unsigned)gx < 128u)
            v = *(const i32x4*)(in + (((size_t)n * 128 + gy) * 128 + gx) * 64 + c16 * 8);
        *(i32x4*)((char*)tileS + pt * 128 + ((c16 ^ (pt & 7)) << 4)) = v;
    }

    const short* wbase = wT + ((MODE == 3) ? (size_t)og * 36864 : 0);
    int aoc = tid >> 3, ac8 = tid & 7;
    i32x4 sa0 = *(const i32x4*)(wbase + (size_t)aoc * 576 + ac8 * 8);
    i32x4 sa1 = *(const i32x4*)(wbase + (size_t)(aoc + 32) * 576 + ac8 * 8);

    f32x4 acc[4][2];
    #pragma unroll
    for (int m = 0; m < 4; ++m) {
        acc[m][0] = (f32x4){0.f, 0.f, 0.f, 0.f};
        acc[m][1] = (f32x4){0.f, 0.f, 0.f, 0.f};
    }

    int p0 = 2 * wv, p1 = 2 * wv + 1;
    int pby0 = (p0 >> 2) << 2, pbx0 = (p0 & 3) << 2;
    int pby1 = (p1 >> 2) << 2, pbx1 = (p1 & 3) << 2;
    int cy = c >> 2, cx = c & 3;

    __syncthreads();  // tile ready

    for (int tap = 0; tap < 9; ++tap) {
        *(i32x4*)((char*)aS + aoc * 128 + ((ac8 ^ (aoc & 7)) << 4)) = sa0;
        *(i32x4*)((char*)aS + (aoc + 32) * 128 + ((ac8 ^ ((aoc + 32) & 7)) << 4)) = sa1;
        if (tap < 8) {
            sa0 = *(const i32x4*)(wbase + (size_t)aoc * 576 + (tap + 1) * 64 + ac8 * 8);
            sa1 = *(const i32x4*)(wbase + (size_t)(aoc + 32) * 576 + (tap + 1) * 64 + ac8 * 8);
        }
        __syncthreads();  // aS ready

        int dty = tap / 3, dtx = tap - dty * 3;
        int pta = (pby0 + cy + dty) * 18 + pbx0 + cx + dtx;
        int ptb = (pby1 + cy + dty) * 18 + pbx1 + cx + dtx;
        #pragma unroll
        for (int ih = 0; ih < 2; ++ih) {
            int slot = ih * 4 + q;
            s16x8 bf0 = *(const s16x8*)((const char*)tileS + pta * 128 + ((slot ^ (pta & 7)) << 4));
            s16x8 bf1 = *(const s16x8*)((const char*)tileS + ptb * 128 + ((slot ^ (ptb & 7)) << 4));
            #pragma unroll
            for (int m = 0; m < 4; ++m) {
                int ocl = m * 16 + c;
                s16x8 a = *(const s16x8*)((const char*)aS + ocl * 128 + ((slot ^ (ocl & 7)) << 4));
                acc[m][0] = __builtin_amdgcn_mfma_f32_16x16x32_bf16(a, bf0, acc[m][0], 0, 0, 0);
                acc[m][1] = __builtin_amdgcn_mfma_f32_16x16x32_bf16(a, bf1, acc[m][1], 0, 0, 0);
            }
        }
        __syncthreads();  // done reading aS
    }

    #pragma unroll
    for (int p = 0; p < 2; ++p) {
        int pby = p ? pby1 : pby0;
        int pbx = p ? pbx1 : pbx0;
        int y = by + pby + cy;
        int x = bx + pbx + cx;
        size_t pxi = ((size_t)n * 128 + y) * 128 + x;
        float fy = 0.f, fx2 = 0.f;
        if (MODE == 3) {
            fy  = flow[(size_t)(n * 2 + 1) * 16384 + y * 128 + x];
            fx2 = flow[(size_t)(n * 2 + 0) * 16384 + y * 128 + x];
        }
        #pragma unroll
        for (int m = 0; m < 4; ++m) {
            int o0 = m * 16 + q * 4;
            f32x4 v = acc[m][p];
            if (MODE == 0) {
                *(f32x4*)(partial + pxi * 64 + o0) = v;
            } else if (MODE == 1 || MODE == 2) {
                f32x4 bv = *(const f32x4*)(bias + o0);
                if (MODE == 1) {
                    f32x4 pv = *(const f32x4*)(partial + pxi * 64 + o0);
                    v += pv;
                }
                v += bv;
                s16x4 r;
                #pragma unroll
                for (int j = 0; j < 4; ++j) {
                    float t = v[j];
                    t = t >= 0.f ? t : 0.1f * t;
                    r[j] = f2bf(t);
                }
                *(s16x4*)(outB + pxi * 64 + o0) = r;
            } else {  // MODE 3
                int oc4 = og * 64 + o0;
                if (oc4 < 432) {
                    f32x4 bv = *(const f32x4*)(bias + oc4);
                    v += bv;
                    s16x4 r;
                    if (oc4 < 288) {
                        v[0] += fy; v[1] += fx2; v[2] += fy; v[3] += fx2;
                        #pragma unroll
                        for (int j = 0; j < 4; ++j) r[j] = f2h(v[j]);
                    } else {
                        #pragma unroll
                        for (int j = 0; j < 4; ++j) r[j] = f2h(1.f / (1.f + expf(-v[j])));
                    }
                    size_t nrel = (size_t)(bid >> 7);
                    *(s16x4*)(offmask + (nrel * 16384 + y * 128 + x) * 432 + oc4) = r;
                }
            }
        }
    }
}

// ---------------------------------------------------------------------------
// DCN: barrier-free, zero-LDS (round-3-proven). Wave = one 4x4 patch; samples
// -> B-frags in regs; dcwT A-frags from L2; MFMA einsum; lrelu -> NCHW out.
// Grid scaled to 4-image chunks: 1024 blocks x 4 waves = 4096 patches.
// ---------------------------------------------------------------------------
__global__ __launch_bounds__(256) void k_dcn(
    const short* __restrict__ offmask, const short* __restrict__ nbrH,
    const short* __restrict__ dcwT, const float* __restrict__ dcb,
    float* __restrict__ out, int n0)
{
    int tid = threadIdx.x;
    int ln = tid & 63, wv = tid >> 6;
    int patch = blockIdx.x * 4 + wv;
    int nrel = patch >> 10;
    int pl = patch & 1023;
    int by = (pl >> 5) << 2, bx = (pl & 31) << 2;
    int n = n0 + nrel;
    int c = ln & 15, q = ln >> 4;
    int y = by + (c >> 2), x = bx + (c & 3);
    const short* om = offmask + ((size_t)nrel * 16384 + y * 128 + x) * 432;
    const short* nb = nbrH + (size_t)n * 16384 * 64;

    s16x8 bfrag[18];
    #pragma unroll
    for (int tap = 0; tap < 9; ++tap) {
        int dty = tap / 3 - 1, dtx = tap - (tap / 3) * 3 - 1;
        #pragma unroll
        for (int ih = 0; ih < 2; ++ih) {
            s16x8 bf;
            #pragma unroll
            for (int hh = 0; hh < 2; ++hh) {
                int g = (ih * 32 + q * 8) / 4 + hh;
                int gk = g * 9 + tap;
                int dd = *(const int*)(om + 2 * gk);
                float dyv = h2f((short)(dd & 0xffff));
                float dxv = h2f((short)(dd >> 16));
                float mk  = h2f(om[288 + gk]);
                float sy = (float)(y + dty) + dyv;
                float sx = (float)(x + dtx) + dxv;
                float y0f = floorf(sy), x0f = floorf(sx);
                int y0 = (int)y0f, x0 = (int)x0f;
                float ddy = sy - y0f, ddx = sx - x0f;
                float vy0 = ((unsigned)y0 < 128u) ? 1.f : 0.f;
                float vy1 = ((unsigned)(y0 + 1) < 128u) ? 1.f : 0.f;
                float vx0 = ((unsigned)x0 < 128u) ? 1.f : 0.f;
                float vx1 = ((unsigned)(x0 + 1) < 128u) ? 1.f : 0.f;
                float w00 = (1.f - ddy) * (1.f - ddx) * vy0 * vx0;
                float w01 = (1.f - ddy) * ddx * vy0 * vx1;
                float w10 = ddy * (1.f - ddx) * vy1 * vx0;
                float w11 = ddy * ddx * vy1 * vx1;
                int y0c = min(max(y0, 0), 127), y1c = min(max(y0 + 1, 0), 127);
                int x0c = min(max(x0, 0), 127), x1c = min(max(x0 + 1, 0), 127);
                s16x4 v00 = *(const s16x4*)(nb + (y0c * 128 + x0c) * 64 + g * 4);
                s16x4 v01 = *(const s16x4*)(nb + (y0c * 128 + x1c) * 64 + g * 4);
                s16x4 v10 = *(const s16x4*)(nb + (y1c * 128 + x0c) * 64 + g * 4);
                s16x4 v11 = *(const s16x4*)(nb + (y1c * 128 + x1c) * 64 + g * 4);
                #pragma unroll
                for (int cc = 0; cc < 4; ++cc) {
                    float sv = w00 * b2f(v00[cc]) + w01 * b2f(v01[cc]) +
                               w10 * b2f(v10[cc]) + w11 * b2f(v11[cc]);
                    bf[hh * 4 + cc] = f2bf(sv * mk);
                }
            }
            bfrag[tap * 2 + ih] = bf;
        }
    }

    f32x4 acc[4];
    #pragma unroll
    for (int m = 0; m < 4; ++m) acc[m] = (f32x4){0.f, 0.f, 0.f, 0.f};
    #pragma unroll
    for (int kc = 0; kc < 18; ++kc) {
        int tap = kc >> 1, ih = kc & 1;
        int ic0 = ih * 32 + q * 8;
        #pragma unroll
        for (int m = 0; m < 4; ++m) {
            s16x8 a = *(const s16x8*)(dcwT + ((size_t)(m * 16 + c) * 9 + tap) * 64 + ic0);
            acc[m] = __builtin_amdgcn_mfma_f32_16x16x32_bf16(a, bfrag[kc], acc[m], 0, 0, 0);
        }
    }
    #pragma unroll
    for (int m = 0; m < 4; ++m) {
        int o0 = m * 16 + q * 4;
        f32x4 bv = *(const f32x4*)(dcb + o0);
        f32x4 v = acc[m] + bv;
        #pragma unroll
        for (int j = 0; j < 4; ++j) {
            float t = v[j];
            t = t >= 0.f ? t : 0.1f * t;
            out[((size_t)n * 64 + o0 + j) * 16384 + y * 128 + x] = t;
        }
    }
}

// ---------------------------------------------------------------------------
extern "C" void kernel_launch(void* const* d_in, const int* in_sizes, int n_in,
                              void* d_out, int out_size, void* d_ws, size_t ws_size,
                              hipStream_t stream)
{
    const float* nbr  = (const float*)d_in[0];
    const float* ref  = (const float*)d_in[1];
    const float* flow = (const float*)d_in[2];
    const float* w1   = (const float*)d_in[3];
    const float* b1   = (const float*)d_in[4];
    const float* w2   = (const float*)d_in[5];
    const float* b2   = (const float*)d_in[6];
    const float* w3   = (const float*)d_in[7];
    const float* b3   = (const float*)d_in[8];
    const float* w4   = (const float*)d_in[9];
    const float* b4   = (const float*)d_in[10];
    const float* dcw  = (const float*)d_in[11];
    const float* dcb  = (const float*)d_in[12];
    float* out = (float*)d_out;
    char* ws = (char*)d_ws;

    // ws layout (bytes), peak 91.23 MB (<=100.66 MB proven in round 2).
    // lifetimes:  h1p written conv1-p1, read conv1-p2, then dead.
    //             h3 [74448896,91226112) overlaps h1p tail only after h1p dead.
    //             offmask [17825792,74448896) overlaps warped/refH/h1p, all
    //             dead by conv4 phase.
    short* nbrH   = (short*)ws;                  // [0, 16777216)
    short* wpool  = (short*)(ws + 16777216);     // [16777216, 17661952)
    short* warped = (short*)(ws + 17825792);     // -> h1 after conv1
    short* refH   = (short*)(ws + 34603008);     // -> h2 after conv2
    float* h1p    = (float*)(ws + 51380224);     // fp32 partial, 33.55 MB
    short* offmask= (short*)(ws + 17825792);     // conv4/dcn phase, 56.6 MB
    short* h3     = (short*)(ws + 74448896);
    short* h1     = warped;
    short* h2     = refH;

    short* wT1a = wpool;            // w1 ic 0-63
    short* wT1b = wpool + 36864;    // w1 ic 64-127
    short* wT2  = wpool + 73728;
    short* wT3  = wpool + 110592;
    short* wT4  = wpool + 147456;   // [448][9][64]
    short* dcwT = wpool + 405504;

    k_wt_all<<<1728, 256, 0, stream>>>(w1, w2, w3, w4, dcw, wpool);
    k_nhwc2<<<1024, 256, 0, stream>>>(nbr, ref, nbrH, refH);
    k_backwarp<<<2048, 256, 0, stream>>>(nbrH, flow, warped);

    // conv1 as two IC-64 passes (round-3-proven)
    k_conv<0><<<1024, 256, 0, stream>>>(warped, wT1a, nullptr, h1p, nullptr, nullptr, nullptr, 0);
    k_conv<1><<<1024, 256, 0, stream>>>(refH, wT1b, b1, h1p, h1, nullptr, nullptr, 0);
    k_conv<2><<<1024, 256, 0, stream>>>(h1, wT2, b2, nullptr, h2, nullptr, nullptr, 0);
    k_conv<2><<<1024, 256, 0, stream>>>(h2, wT3, b3, nullptr, h3, nullptr, nullptr, 0);

    for (int n0 = 0; n0 < 8; n0 += 4) {
        dim3 g4(512, 7);
        k_conv<3><<<g4, 256, 0, stream>>>(h3, wT4, b4, nullptr, nullptr, offmask, flow, n0);
        k_dcn<<<1024, 256, 0, stream>>>(offmask, nbrH, dcwT, dcb, out, n0);
    }
}

// Round 8
// 365.576 us; speedup vs baseline: 2.0049x; 1.1923x over previous
//
#include <hip/hip_runtime.h>
#include <math.h>

#define H 128
#define W 128
#define NB 8
#define NFC 64

typedef __attribute__((ext_vector_type(8))) short s16x8;
typedef __attribute__((ext_vector_type(4))) short s16x4;
typedef __attribute__((ext_vector_type(4))) float f32x4;
typedef __attribute__((ext_vector_type(4))) int   i32x4;
typedef __attribute__((ext_vector_type(2))) int   i32x2;

__device__ __forceinline__ float b2f(short s) {
    return __uint_as_float(((unsigned)(unsigned short)s) << 16);
}
__device__ __forceinline__ short f2bf(float f) {
    unsigned u = __float_as_uint(f);
    u += 0x7FFF + ((u >> 16) & 1);
    return (short)(u >> 16);
}
__device__ __forceinline__ short f2h(float f) {
    _Float16 h = (_Float16)f;
    return __builtin_bit_cast(short, h);
}
__device__ __forceinline__ float h2f(short s) {
    return (float)__builtin_bit_cast(_Float16, s);
}

// ---------------------------------------------------------------------------
// all weight transforms in one launch -> wpool bf16 [768][9][64]
// ---------------------------------------------------------------------------
__global__ __launch_bounds__(256) void k_wt_all(
    const float* __restrict__ w1, const float* __restrict__ w2,
    const float* __restrict__ w3, const float* __restrict__ w4,
    const float* __restrict__ dcw, short* __restrict__ wp)
{
    int idx = blockIdx.x * 256 + threadIdx.x;   // < 442368
    int u = idx / 576;
    int r = idx - u * 576;
    int t = r >> 6, i = r & 63;
    float v;
    if (u < 128) {
        int o = u & 63, icoff = (u >> 6) << 6;
        v = w1[((size_t)(o * 128) + icoff + i) * 9 + t];
    } else if (u < 192) {
        int o = u - 128;
        v = w2[((size_t)(o * 64) + i) * 9 + t];
    } else if (u < 256) {
        int o = u - 192;
        v = w3[((size_t)(o * 64) + i) * 9 + t];
    } else if (u < 704) {
        int o = u - 256;
        v = (o < 432) ? w4[((size_t)(o * 64) + i) * 9 + t] : 0.f;
    } else {
        int o = u - 704;
        v = dcw[((size_t)(o * 64) + i) * 9 + t];
    }
    wp[idx] = f2bf(v);
}

// ---------------------------------------------------------------------------
// NCHW fp32 -> (nbr: g-planar bf16 [n][16][128][128][4]) and (ref: NHWC bf16)
// ---------------------------------------------------------------------------
__global__ __launch_bounds__(256) void k_nhwc2(const float* __restrict__ nbr,
                                               const float* __restrict__ ref,
                                               short* __restrict__ nbrG,
                                               short* __restrict__ refH)
{
    int px = blockIdx.x * 256 + threadIdx.x;
    bool isNbr = (px < 131072);
    const float* src;
    if (isNbr) { src = nbr; }
    else       { src = ref; px -= 131072; }
    int n = px >> 14;
    int sp = px & 16383;
    const float* s = src + (size_t)n * 64 * 16384 + sp;
    unsigned pk[32];
    #pragma unroll
    for (int c = 0; c < 32; ++c) {
        float v0 = s[(size_t)(2 * c) * 16384];
        float v1 = s[(size_t)(2 * c + 1) * 16384];
        pk[c] = (unsigned)(unsigned short)f2bf(v0) |
                ((unsigned)(unsigned short)f2bf(v1) << 16);
    }
    if (isNbr) {
        #pragma unroll
        for (int g = 0; g < 16; ++g) {
            i32x2 t;
            t[0] = pk[2 * g]; t[1] = pk[2 * g + 1];
            *(i32x2*)(nbrG + ((size_t)(n * 16 + g) * 16384 + sp) * 4) = t;
        }
    } else {
        i32x4* d = (i32x4*)(refH + (size_t)(n * 16384 + sp) * 64);
        #pragma unroll
        for (int qq = 0; qq < 8; ++qq) {
            i32x4 t;
            t[0] = pk[4 * qq]; t[1] = pk[4 * qq + 1];
            t[2] = pk[4 * qq + 2]; t[3] = pk[4 * qq + 3];
            d[qq] = t;
        }
    }
}

// ---------------------------------------------------------------------------
// backwarp: nbrG (g-planar bf16) + flow -> warped (NHWC bf16)
// row-pair 16B loads + clamp-selects (numerics identical to 4x8B version)
// ---------------------------------------------------------------------------
__global__ __launch_bounds__(256) void k_backwarp(const short* __restrict__ nbrG,
                                                  const float* __restrict__ flow,
                                                  short* __restrict__ warped)
{
    int idx = blockIdx.x * 256 + threadIdx.x;
    int px = idx >> 2, qt = idx & 3;
    int n = px >> 14;
    int x = px & 127, y = (px >> 7) & 127;
    float fx = flow[(size_t)(n * 2 + 0) * 16384 + y * 128 + x];
    float fy = flow[(size_t)(n * 2 + 1) * 16384 + y * 128 + x];
    float pxf = (float)x + fx, pyf = (float)y + fy;
    float x0f = floorf(pxf), y0f = floorf(pyf);
    int x0 = (int)x0f, y0 = (int)y0f;
    float dx = pxf - x0f, dy = pyf - y0f;
    float vy0 = ((unsigned)y0 < 128u) ? 1.f : 0.f;
    float vy1 = ((unsigned)(y0 + 1) < 128u) ? 1.f : 0.f;
    float vx0 = ((unsigned)x0 < 128u) ? 1.f : 0.f;
    float vx1 = ((unsigned)(x0 + 1) < 128u) ? 1.f : 0.f;
    float w00 = (1.f - dy) * (1.f - dx) * vy0 * vx0;
    float w01 = (1.f - dy) * dx * vy0 * vx1;
    float w10 = dy * (1.f - dx) * vy1 * vx0;
    float w11 = dy * dx * vy1 * vx1;
    int y0c = min(max(y0, 0), 127), y1c = min(max(y0 + 1, 0), 127);
    int x0c = min(max(x0, 0), 127), x1c = min(max(x0 + 1, 0), 127);
    int xb = min(max(x0, 0), 126);
    bool s0 = (x0c == xb), s1 = (x1c == xb);

    const short* plbase = nbrG + (size_t)n * 16 * 65536;
    s16x8 r0, r1;
    #pragma unroll
    for (int pg = 0; pg < 4; ++pg) {
        const short* pl = plbase + (size_t)(qt * 4 + pg) * 65536;
        s16x8 p0 = *(const s16x8*)(pl + (y0c * 128 + xb) * 4);
        s16x8 p1 = *(const s16x8*)(pl + (y1c * 128 + xb) * 4);
        #pragma unroll
        for (int cc = 0; cc < 4; ++cc) {
            float v00 = b2f(s0 ? p0[cc] : p0[4 + cc]);
            float v01 = b2f(s1 ? p0[cc] : p0[4 + cc]);
            float v10 = b2f(s0 ? p1[cc] : p1[4 + cc]);
            float v11 = b2f(s1 ? p1[cc] : p1[4 + cc]);
            float v = w00 * v00 + w01 * v01 + w10 * v10 + w11 * v11;
            short res = f2bf(v);
            if (pg < 2) r0[pg * 4 + cc] = res;
            else        r1[(pg - 2) * 4 + cc] = res;
        }
    }
    short* o = warped + (size_t)px * 64 + qt * 16;
    *(s16x8*)o = r0;
    *(s16x8*)(o + 8) = r1;
}

// ---------------------------------------------------------------------------
// MFMA conv3x3, IC=64 (round-3-proven structure, unchanged).
// ---------------------------------------------------------------------------
template<int MODE>
__global__ __launch_bounds__(256) void k_conv(
    const short* __restrict__ in, const short* __restrict__ wT,
    const float* __restrict__ bias,
    float* __restrict__ partial, short* __restrict__ outB,
    short* __restrict__ offmask, const float* __restrict__ flow, int n0)
{
    __shared__ __align__(16) short tileS[180 * 64];
    __shared__ __align__(16) short aS[64 * 64];

    int tid = threadIdx.x;
    int bid = blockIdx.x;
    int og = (MODE == 3) ? blockIdx.y : 0;
    int n  = (MODE == 3) ? (n0 + (bid >> 7)) : (bid >> 7);
    int tl = bid & 127;
    int bx = (tl & 7) << 4;
    int by = (tl >> 3) << 3;
    int ln = tid & 63, wv = tid >> 6;
    int c = ln & 15, q = ln >> 4;

    for (int i = tid; i < 1440; i += 256) {
        int pt = i >> 3, c16 = i & 7;
        int ty = pt / 18, tx = pt - ty * 18;
        int gy = by + ty - 1, gx = bx + tx - 1;
        i32x4 v = {0, 0, 0, 0};
        if ((unsigned)gy < 128u && (unsigned)gx < 128u)
            v = *(const i32x4*)(in + (((size_t)n * 128 + gy) * 128 + gx) * 64 + c16 * 8);
        *(i32x4*)((char*)tileS + pt * 128 + ((c16 ^ (pt & 7)) << 4)) = v;
    }

    const short* wbase = wT + ((MODE == 3) ? (size_t)og * 36864 : 0);
    int aoc = tid >> 3, ac8 = tid & 7;
    i32x4 sa0 = *(const i32x4*)(wbase + (size_t)aoc * 576 + ac8 * 8);
    i32x4 sa1 = *(const i32x4*)(wbase + (size_t)(aoc + 32) * 576 + ac8 * 8);

    f32x4 acc[4][2];
    #pragma unroll
    for (int m = 0; m < 4; ++m) {
        acc[m][0] = (f32x4){0.f, 0.f, 0.f, 0.f};
        acc[m][1] = (f32x4){0.f, 0.f, 0.f, 0.f};
    }

    int p0 = 2 * wv, p1 = 2 * wv + 1;
    int pby0 = (p0 >> 2) << 2, pbx0 = (p0 & 3) << 2;
    int pby1 = (p1 >> 2) << 2, pbx1 = (p1 & 3) << 2;
    int cy = c >> 2, cx = c & 3;

    __syncthreads();  // tile ready

    for (int tap = 0; tap < 9; ++tap) {
        *(i32x4*)((char*)aS + aoc * 128 + ((ac8 ^ (aoc & 7)) << 4)) = sa0;
        *(i32x4*)((char*)aS + (aoc + 32) * 128 + ((ac8 ^ ((aoc + 32) & 7)) << 4)) = sa1;
        if (tap < 8) {
            sa0 = *(const i32x4*)(wbase + (size_t)aoc * 576 + (tap + 1) * 64 + ac8 * 8);
            sa1 = *(const i32x4*)(wbase + (size_t)(aoc + 32) * 576 + (tap + 1) * 64 + ac8 * 8);
        }
        __syncthreads();  // aS ready

        int dty = tap / 3, dtx = tap - dty * 3;
        int pta = (pby0 + cy + dty) * 18 + pbx0 + cx + dtx;
        int ptb = (pby1 + cy + dty) * 18 + pbx1 + cx + dtx;
        #pragma unroll
        for (int ih = 0; ih < 2; ++ih) {
            int slot = ih * 4 + q;
            s16x8 bf0 = *(const s16x8*)((const char*)tileS + pta * 128 + ((slot ^ (pta & 7)) << 4));
            s16x8 bf1 = *(const s16x8*)((const char*)tileS + ptb * 128 + ((slot ^ (ptb & 7)) << 4));
            #pragma unroll
            for (int m = 0; m < 4; ++m) {
                int ocl = m * 16 + c;
                s16x8 a = *(const s16x8*)((const char*)aS + ocl * 128 + ((slot ^ (ocl & 7)) << 4));
                acc[m][0] = __builtin_amdgcn_mfma_f32_16x16x32_bf16(a, bf0, acc[m][0], 0, 0, 0);
                acc[m][1] = __builtin_amdgcn_mfma_f32_16x16x32_bf16(a, bf1, acc[m][1], 0, 0, 0);
            }
        }
        __syncthreads();  // done reading aS
    }

    #pragma unroll
    for (int p = 0; p < 2; ++p) {
        int pby = p ? pby1 : pby0;
        int pbx = p ? pbx1 : pbx0;
        int y = by + pby + cy;
        int x = bx + pbx + cx;
        size_t pxi = ((size_t)n * 128 + y) * 128 + x;
        float fy = 0.f, fx2 = 0.f;
        if (MODE == 3) {
            fy  = flow[(size_t)(n * 2 + 1) * 16384 + y * 128 + x];
            fx2 = flow[(size_t)(n * 2 + 0) * 16384 + y * 128 + x];
        }
        #pragma unroll
        for (int m = 0; m < 4; ++m) {
            int o0 = m * 16 + q * 4;
            f32x4 v = acc[m][p];
            if (MODE == 0) {
                *(f32x4*)(partial + pxi * 64 + o0) = v;
            } else if (MODE == 1 || MODE == 2) {
                f32x4 bv = *(const f32x4*)(bias + o0);
                if (MODE == 1) {
                    f32x4 pv = *(const f32x4*)(partial + pxi * 64 + o0);
                    v += pv;
                }
                v += bv;
                s16x4 r;
                #pragma unroll
                for (int j = 0; j < 4; ++j) {
                    float t = v[j];
                    t = t >= 0.f ? t : 0.1f * t;
                    r[j] = f2bf(t);
                }
                *(s16x4*)(outB + pxi * 64 + o0) = r;
            } else {  // MODE 3
                int oc4 = og * 64 + o0;
                if (oc4 < 432) {
                    f32x4 bv = *(const f32x4*)(bias + oc4);
                    v += bv;
                    s16x4 r;
                    if (oc4 < 288) {
                        v[0] += fy; v[1] += fx2; v[2] += fy; v[3] += fx2;
                        #pragma unroll
                        for (int j = 0; j < 4; ++j) r[j] = f2h(v[j]);
                    } else {
                        #pragma unroll
                        for (int j = 0; j < 4; ++j) r[j] = f2h(1.f / (1.f + expf(-v[j])));
                    }
                    size_t nrel = (size_t)(bid >> 7);
                    *(s16x4*)(offmask + (nrel * 16384 + y * 128 + x) * 432 + oc4) = r;
                }
            }
        }
    }
}

// ---------------------------------------------------------------------------
// DCN: barrier-free, zero-LDS. Wave = one 4x4 patch. g-planar nbr sampling:
// per sample, 2x 16B row-pair loads + clamp-selects (was 4x 8B gathers).
// ---------------------------------------------------------------------------
__global__ __launch_bounds__(256) void k_dcn(
    const short* __restrict__ offmask, const short* __restrict__ nbrG,
    const short* __restrict__ dcwT, const float* __restrict__ dcb,
    float* __restrict__ out, int n0)
{
    int tid = threadIdx.x;
    int ln = tid & 63, wv = tid >> 6;
    int patch = blockIdx.x * 4 + wv;
    int nrel = patch >> 10;
    int pl = patch & 1023;
    int by = (pl >> 5) << 2, bx = (pl & 31) << 2;
    int n = n0 + nrel;
    int c = ln & 15, q = ln >> 4;
    int y = by + (c >> 2), x = bx + (c & 3);
    const short* om = offmask + ((size_t)nrel * 16384 + y * 128 + x) * 432;
    const short* plbase = nbrG + (size_t)n * 16 * 65536;

    s16x8 bfrag[18];
    #pragma unroll
    for (int tap = 0; tap < 9; ++tap) {
        int dty = tap / 3 - 1, dtx = tap - (tap / 3) * 3 - 1;
        #pragma unroll
        for (int ih = 0; ih < 2; ++ih) {
            s16x8 bf;
            #pragma unroll
            for (int hh = 0; hh < 2; ++hh) {
                int g = ih * 8 + q * 2 + hh;
                int gk = g * 9 + tap;
                int dd = *(const int*)(om + 2 * gk);
                float dyv = h2f((short)(dd & 0xffff));
                float dxv = h2f((short)(dd >> 16));
                float mk  = h2f(om[288 + gk]);
                float sy = (float)(y + dty) + dyv;
                float sx = (float)(x + dtx) + dxv;
                float y0f = floorf(sy), x0f = floorf(sx);
                int y0 = (int)y0f, x0 = (int)x0f;
                float ddy = sy - y0f, ddx = sx - x0f;
                float vy0 = ((unsigned)y0 < 128u) ? 1.f : 0.f;
                float vy1 = ((unsigned)(y0 + 1) < 128u) ? 1.f : 0.f;
                float vx0 = ((unsigned)x0 < 128u) ? 1.f : 0.f;
                float vx1 = ((unsigned)(x0 + 1) < 128u) ? 1.f : 0.f;
                float w00 = (1.f - ddy) * (1.f - ddx) * vy0 * vx0;
                float w01 = (1.f - ddy) * ddx * vy0 * vx1;
                float w10 = ddy * (1.f - ddx) * vy1 * vx0;
                float w11 = ddy * ddx * vy1 * vx1;
                int y0c = min(max(y0, 0), 127), y1c = min(max(y0 + 1, 0), 127);
                int x0c = min(max(x0, 0), 127), x1c = min(max(x0 + 1, 0), 127);
                int xb = min(max(x0, 0), 126);
                bool sel0 = (x0c == xb), sel1 = (x1c == xb);
                const short* plg = plbase + (size_t)g * 65536;
                s16x8 pr0 = *(const s16x8*)(plg + (y0c * 128 + xb) * 4);
                s16x8 pr1 = *(const s16x8*)(plg + (y1c * 128 + xb) * 4);
                #pragma unroll
                for (int cc = 0; cc < 4; ++cc) {
                    float v00 = b2f(sel0 ? pr0[cc] : pr0[4 + cc]);
                    float v01 = b2f(sel1 ? pr0[cc] : pr0[4 + cc]);
                    float v10 = b2f(sel0 ? pr1[cc] : pr1[4 + cc]);
                    float v11 = b2f(sel1 ? pr1[cc] : pr1[4 + cc]);
                    float sv = w00 * v00 + w01 * v01 + w10 * v10 + w11 * v11;
                    bf[hh * 4 + cc] = f2bf(sv * mk);
                }
            }
            bfrag[tap * 2 + ih] = bf;
        }
    }

    f32x4 acc[4];
    #pragma unroll
    for (int m = 0; m < 4; ++m) acc[m] = (f32x4){0.f, 0.f, 0.f, 0.f};
    #pragma unroll
    for (int kc = 0; kc < 18; ++kc) {
        int tap = kc >> 1, ih = kc & 1;
        int ic0 = ih * 32 + q * 8;
        #pragma unroll
        for (int m = 0; m < 4; ++m) {
            s16x8 a = *(const s16x8*)(dcwT + ((size_t)(m * 16 + c) * 9 + tap) * 64 + ic0);
            acc[m] = __builtin_amdgcn_mfma_f32_16x16x32_bf16(a, bfrag[kc], acc[m], 0, 0, 0);
        }
    }
    #pragma unroll
    for (int m = 0; m < 4; ++m) {
        int o0 = m * 16 + q * 4;
        f32x4 bv = *(const f32x4*)(dcb + o0);
        f32x4 v = acc[m] + bv;
        #pragma unroll
        for (int j = 0; j < 4; ++j) {
            float t = v[j];
            t = t >= 0.f ? t : 0.1f * t;
            out[((size_t)n * 64 + o0 + j) * 16384 + y * 128 + x] = t;
        }
    }
}

// ---------------------------------------------------------------------------
extern "C" void kernel_launch(void* const* d_in, const int* in_sizes, int n_in,
                              void* d_out, int out_size, void* d_ws, size_t ws_size,
                              hipStream_t stream)
{
    const float* nbr  = (const float*)d_in[0];
    const float* ref  = (const float*)d_in[1];
    const float* flow = (const float*)d_in[2];
    const float* w1   = (const float*)d_in[3];
    const float* b1   = (const float*)d_in[4];
    const float* w2   = (const float*)d_in[5];
    const float* b2   = (const float*)d_in[6];
    const float* w3   = (const float*)d_in[7];
    const float* b3   = (const float*)d_in[8];
    const float* w4   = (const float*)d_in[9];
    const float* b4   = (const float*)d_in[10];
    const float* dcw  = (const float*)d_in[11];
    const float* dcb  = (const float*)d_in[12];
    float* out = (float*)d_out;
    char* ws = (char*)d_ws;

    // ws layout (bytes), peak 91.23 MB (<=100.66 MB proven in round 2).
    short* nbrG   = (short*)ws;                  // [0, 16777216) g-planar
    short* wpool  = (short*)(ws + 16777216);     // [16777216, 17661952)
    short* warped = (short*)(ws + 17825792);     // -> h1 after conv1
    short* refH   = (short*)(ws + 34603008);     // -> h2 after conv2
    float* h1p    = (float*)(ws + 51380224);     // fp32 partial, 33.55 MB
    short* offmask= (short*)(ws + 17825792);     // conv4/dcn phase, 56.6 MB
    short* h3     = (short*)(ws + 74448896);
    short* h1     = warped;
    short* h2     = refH;

    short* wT1a = wpool;            // w1 ic 0-63
    short* wT1b = wpool + 36864;    // w1 ic 64-127
    short* wT2  = wpool + 73728;
    short* wT3  = wpool + 110592;
    short* wT4  = wpool + 147456;   // [448][9][64]
    short* dcwT = wpool + 405504;

    k_wt_all<<<1728, 256, 0, stream>>>(w1, w2, w3, w4, dcw, wpool);
    k_nhwc2<<<1024, 256, 0, stream>>>(nbr, ref, nbrG, refH);
    k_backwarp<<<2048, 256, 0, stream>>>(nbrG, flow, warped);

    // conv1 as two IC-64 passes
    k_conv<0><<<1024, 256, 0, stream>>>(warped, wT1a, nullptr, h1p, nullptr, nullptr, nullptr, 0);
    k_conv<1><<<1024, 256, 0, stream>>>(refH, wT1b, b1, h1p, h1, nullptr, nullptr, 0);
    k_conv<2><<<1024, 256, 0, stream>>>(h1, wT2, b2, nullptr, h2, nullptr, nullptr, 0);
    k_conv<2><<<1024, 256, 0, stream>>>(h2, wT3, b3, nullptr, h3, nullptr, nullptr, 0);

    for (int n0 = 0; n0 < 8; n0 += 4) {
        dim3 g4(512, 7);
        k_conv<3><<<g4, 256, 0, stream>>>(h3, wT4, b4, nullptr, nullptr, offmask, flow, n0);
        k_dcn<<<1024, 256, 0, stream>>>(offmask, nbrG, dcwT, dcb, out, n0);
    }
}